// Round 1
// baseline (327.663 us; speedup 1.0000x reference)
//
#include <hip/hip_runtime.h>
#include <math.h>

#define NB 32
#define CB 256
#define HB 56
#define WB 56
#define PLANE (HB*WB)        // 3136
#define CL 56                // per-axis length
#define POOLSZ (NB*CB*CL)    // 458752 floats per pool buffer

__device__ inline float wave_sum(float v) {
    #pragma unroll
    for (int o = 32; o; o >>= 1) v += __shfl_xor(v, o, 64);
    return v;
}

// ---------------- Kernel 1: pooling (mean/max over rows & cols + global mean) ----
__global__ __launch_bounds__(64) void k_pool(const float* __restrict__ x,
                                             float* __restrict__ ph, float* __restrict__ pw,
                                             float* __restrict__ mh, float* __restrict__ mw,
                                             float* __restrict__ gap) {
    int b = blockIdx.x;                  // b = n*256 + c
    const float* xp = x + (size_t)b * PLANE;
    __shared__ float tile[HB * 57];      // +1 pad -> stride 57 (25 mod 32, coprime)
    int t = threadIdx.x;                 // 64 threads
    for (int i = t; i < PLANE; i += 64) {
        int h = i / WB, w = i - h * WB;
        tile[h * 57 + w] = xp[i];
    }
    __syncthreads();
    float csum = 0.f, cmax = -INFINITY, rsum = 0.f, rmax = -INFINITY;
    if (t < CL) {
        #pragma unroll 4
        for (int h = 0; h < HB; ++h) {   // column t scan: consecutive banks, conflict-free
            float v = tile[h * 57 + t];
            csum += v; cmax = fmaxf(cmax, v);
        }
        #pragma unroll 4
        for (int w = 0; w < WB; ++w) {   // row t scan: stride-57 across lanes, 2-way (free)
            float v = tile[t * 57 + w];
            rsum += v; rmax = fmaxf(rmax, v);
        }
    }
    float tot = wave_sum(rsum);          // lanes >=56 contribute 0
    if (t < CL) {
        size_t idx = (size_t)b * CL + t;
        ph[idx] = rsum * (1.f / WB);
        mh[idx] = rmax;
        pw[idx] = csum * (1.f / HB);
        mw[idx] = cmax;
    }
    if (t == 0) gap[b] = tot * (1.f / PLANE);
}

// ---------------- Kernel 2: branch MLPs (+ gate g on branch 0) -------------------
__global__ __launch_bounds__(256) void k_branch(
        const float* __restrict__ ph, const float* __restrict__ pw,
        const float* __restrict__ mh, const float* __restrict__ mw,
        const float* __restrict__ gap,
        const float* __restrict__ w1, const float* __restrict__ b1,
        const float* __restrict__ gamma, const float* __restrict__ beta,
        const float* __restrict__ rmean, const float* __restrict__ rvar,
        const float* __restrict__ wh, const float* __restrict__ bh,
        const float* __restrict__ ww, const float* __restrict__ bw,
        const float* __restrict__ gw1, const float* __restrict__ gw2,
        const float* __restrict__ gb2,
        float* __restrict__ ah_m, float* __restrict__ aw_m,
        float* __restrict__ ah_x, float* __restrict__ aw_x,
        float* __restrict__ g) {
    int n = blockIdx.x;
    int br = blockIdx.y;                              // 0 = mean branch, 1 = max branch
    const float* pool_h = br ? mh : ph;
    const float* pool_w = br ? mw : pw;
    float* out_ah = br ? ah_x : ah_m;
    float* out_aw = br ? aw_x : aw_m;
    __shared__ float y[8 * 112];
    __shared__ float hid[64];
    int t = threadIdx.x;                              // 256 threads

    // y[m,l] = relu(BN(sum_c pool[c,l] * w1[m,c] + b1[m]))
    for (int idx = t; idx < 8 * 112; idx += 256) {
        int m = idx / 112, l = idx - m * 112;
        const float* src = (l < CL) ? (pool_h + (size_t)n * (CB * CL) + l)
                                    : (pool_w + (size_t)n * (CB * CL) + (l - CL));
        float acc = 0.f;
        for (int c = 0; c < CB; ++c) acc += src[(size_t)c * CL] * w1[m * CB + c];
        acc += b1[m];
        float scale = gamma[m] * rsqrtf(rvar[m] + 1e-5f);
        acc = (acc - rmean[m]) * scale + beta[m];
        y[idx] = fmaxf(acc, 0.f);
    }
    __syncthreads();

    // ah[o,l] = sigmoid(sum_m y[m,l]*wh[o,m] + bh[o]);  aw from y[:,56:] with ww
    for (int idx = t; idx < CB * CL; idx += 256) {
        int o = idx / CL, l = idx - o * CL;
        float acc = bh[o], acc2 = bw[o];
        #pragma unroll
        for (int m = 0; m < 8; ++m) {
            acc  += y[m * 112 + l]      * wh[o * 8 + m];
            acc2 += y[m * 112 + CL + l] * ww[o * 8 + m];
        }
        out_ah[(size_t)n * (CB * CL) + idx] = 1.f / (1.f + __expf(-acc));
        out_aw[(size_t)n * (CB * CL) + idx] = 1.f / (1.f + __expf(-acc2));
    }

    if (br == 0) {   // gate g[n] = softmax(relu(gap@gw1.T)@gw2.T + gb2)
        if (t < 64) {
            float a = 0.f;
            for (int c = 0; c < CB; ++c) a += gap[n * CB + c] * gw1[t * CB + c];
            hid[t] = fmaxf(a, 0.f);
        }
        __syncthreads();
        if (t == 0) {
            float l0 = gb2[0], l1 = gb2[1];
            for (int j = 0; j < 64; ++j) { l0 += hid[j] * gw2[j]; l1 += hid[j] * gw2[64 + j]; }
            float mx = fmaxf(l0, l1);
            float e0 = __expf(l0 - mx), e1 = __expf(l1 - mx);
            float inv = 1.f / (e0 + e1);
            g[n * 2]     = e0 * inv;
            g[n * 2 + 1] = e1 * inv;
        }
    }
}

// ---------------- Kernel 3: t[n,c] = mean_{h,w} x * attn -------------------------
__global__ __launch_bounds__(64) void k_tsum(const float* __restrict__ x,
        const float* __restrict__ ah_m, const float* __restrict__ aw_m,
        const float* __restrict__ ah_x, const float* __restrict__ aw_x,
        const float* __restrict__ g, float* __restrict__ tvec) {
    int b = blockIdx.x;                   // n*256 + c
    int n = b >> 8;
    int t = threadIdx.x;
    size_t abase = (size_t)b * CL;
    float vahm = 0.f, vawm = 0.f, vahx = 0.f, vawx = 0.f;
    if (t < CL) {
        vahm = ah_m[abase + t]; vawm = aw_m[abase + t];
        vahx = ah_x[abase + t]; vawx = aw_x[abase + t];
    }
    float g0 = g[n * 2], g1 = g[n * 2 + 1];
    float wm = g0 * vawm, wx = g1 * vawx;       // per-lane w-factors (0 for lanes >= 56)
    const float* xp = x + (size_t)b * PLANE;
    float acc = 0.f;
    for (int h = 0; h < HB; ++h) {
        float am = __shfl(vahm, h, 64);
        float ax = __shfl(vahx, h, 64);
        float xv = (t < CL) ? xp[h * WB + t] : 0.f;
        acc += xv * (am * wm + ax * wx);
    }
    acc = wave_sum(acc);
    if (t == 0) tvec[b] = acc * (1.f / PLANE);
}

// ---------------- Kernel 4: s = sigmoid(relu(t@cw1.T)@cw2.T + cb2) ---------------
__global__ __launch_bounds__(256) void k_sgate(const float* __restrict__ tvec,
        const float* __restrict__ cw1, const float* __restrict__ cw2,
        const float* __restrict__ cb2, float* __restrict__ s) {
    int n = blockIdx.x;
    int t = threadIdx.x;                  // 256
    __shared__ float hid[64];
    if (t < 64) {
        float a = 0.f;
        for (int c = 0; c < CB; ++c) a += tvec[n * CB + c] * cw1[t * CB + c];
        hid[t] = fmaxf(a, 0.f);
    }
    __syncthreads();
    float a = cb2[t];
    #pragma unroll 8
    for (int j = 0; j < 64; ++j) a += hid[j] * cw2[t * 64 + j];
    s[n * CB + t] = 1.f / (1.f + __expf(-a));
}

// ---------------- Kernel 5: out = x * (attn*s + 1) -------------------------------
__global__ __launch_bounds__(64) void k_final(const float* __restrict__ x,
        const float* __restrict__ ah_m, const float* __restrict__ aw_m,
        const float* __restrict__ ah_x, const float* __restrict__ aw_x,
        const float* __restrict__ g, const float* __restrict__ s,
        float* __restrict__ out) {
    int b = blockIdx.x;
    int n = b >> 8;
    int t = threadIdx.x;
    size_t abase = (size_t)b * CL;
    float vahm = 0.f, vawm = 0.f, vahx = 0.f, vawx = 0.f;
    if (t < CL) {
        vahm = ah_m[abase + t]; vawm = aw_m[abase + t];
        vahx = ah_x[abase + t]; vawx = aw_x[abase + t];
    }
    float g0 = g[n * 2], g1 = g[n * 2 + 1];
    float sv = s[b];
    float wm = g0 * vawm * sv, wx = g1 * vawx * sv;
    const float* xp = x + (size_t)b * PLANE;
    float* op = out + (size_t)b * PLANE;
    for (int h = 0; h < HB; ++h) {
        float am = __shfl(vahm, h, 64);
        float ax = __shfl(vahx, h, 64);
        if (t < CL) {
            float xv = xp[h * WB + t];
            op[h * WB + t] = xv * (am * wm + ax * wx + 1.f);
        }
    }
}

extern "C" void kernel_launch(void* const* d_in, const int* in_sizes, int n_in,
                              void* d_out, int out_size, void* d_ws, size_t ws_size,
                              hipStream_t stream) {
    const float* x     = (const float*)d_in[0];
    const float* w1    = (const float*)d_in[1];
    const float* b1    = (const float*)d_in[2];
    const float* gamma = (const float*)d_in[3];
    const float* beta  = (const float*)d_in[4];
    const float* rmean = (const float*)d_in[5];
    const float* rvar  = (const float*)d_in[6];
    const float* wh    = (const float*)d_in[7];
    const float* bh    = (const float*)d_in[8];
    const float* ww    = (const float*)d_in[9];
    const float* bw    = (const float*)d_in[10];
    const float* gw1   = (const float*)d_in[11];
    const float* gw2   = (const float*)d_in[12];
    const float* gb2   = (const float*)d_in[13];
    const float* cw1   = (const float*)d_in[14];
    const float* cw2   = (const float*)d_in[15];
    const float* cb2   = (const float*)d_in[16];
    float* out = (float*)d_out;

    float* w = (float*)d_ws;
    float* ph   = w;                 // N*C*56
    float* pw   = ph  + POOLSZ;
    float* mh   = pw  + POOLSZ;
    float* mw   = mh  + POOLSZ;
    float* ah_m = mw  + POOLSZ;
    float* aw_m = ah_m + POOLSZ;
    float* ah_x = aw_m + POOLSZ;
    float* aw_x = ah_x + POOLSZ;
    float* gap  = aw_x + POOLSZ;     // N*C
    float* tvec = gap  + NB * CB;    // N*C
    float* sbuf = tvec + NB * CB;    // N*C
    float* gbuf = sbuf + NB * CB;    // N*2

    int nplanes = NB * CB;           // 8192

    k_pool<<<nplanes, 64, 0, stream>>>(x, ph, pw, mh, mw, gap);
    k_branch<<<dim3(NB, 2), 256, 0, stream>>>(ph, pw, mh, mw, gap,
                                              w1, b1, gamma, beta, rmean, rvar,
                                              wh, bh, ww, bw, gw1, gw2, gb2,
                                              ah_m, aw_m, ah_x, aw_x, gbuf);
    k_tsum<<<nplanes, 64, 0, stream>>>(x, ah_m, aw_m, ah_x, aw_x, gbuf, tvec);
    k_sgate<<<NB, 256, 0, stream>>>(tvec, cw1, cw2, cb2, sbuf);
    k_final<<<nplanes, 64, 0, stream>>>(x, ah_m, aw_m, ah_x, aw_x, gbuf, sbuf, out);
}

// Round 2
// 308.845 us; speedup vs baseline: 1.0609x; 1.0609x over previous
//
#include <hip/hip_runtime.h>
#include <math.h>

#define NB 32
#define CB 256
#define HB 56
#define WB 56
#define PLANE (HB*WB)        // 3136 floats, contiguous per (n,c) plane
#define PLANE4 (PLANE/4)     // 784 float4s; rows are 14 float4 -> no row wrap
#define CL 56
#define POOLSZ (NB*CB*CL)    // floats per pool buffer

__device__ inline float wave_sum(float v) {
    #pragma unroll
    for (int o = 32; o; o >>= 1) v += __shfl_xor(v, o, 64);
    return v;
}

// ---------------- Kernel 1: pooling (row/col mean+max, global mean) --------------
__global__ __launch_bounds__(64) void k_pool(const float* __restrict__ x,
                                             float* __restrict__ ph, float* __restrict__ pw,
                                             float* __restrict__ mh, float* __restrict__ mw,
                                             float* __restrict__ gap) {
    int b = blockIdx.x;                  // n*256 + c
    const float4* xp4 = (const float4*)(x + (size_t)b * PLANE);
    __shared__ float tile[HB * 57];      // stride 57: row scan 2-way (free), col scan clean
    int t = threadIdx.x;
    for (int j = t; j < PLANE4; j += 64) {          // coalesced 1 KiB/wave/instr
        float4 v = xp4[j];
        int h = j / 14, w4 = (j - h * 14) * 4;
        float* d = &tile[h * 57 + w4];
        d[0] = v.x; d[1] = v.y; d[2] = v.z; d[3] = v.w;
    }
    __syncthreads();
    float csum = 0.f, cmax = -INFINITY, rsum = 0.f, rmax = -INFINITY;
    if (t < CL) {
        #pragma unroll 4
        for (int h = 0; h < HB; ++h) {   // column t: consecutive banks across lanes
            float v = tile[h * 57 + t];
            csum += v; cmax = fmaxf(cmax, v);
        }
        #pragma unroll 4
        for (int w = 0; w < WB; ++w) {   // row t: stride-57 across lanes, 2-way (free)
            float v = tile[t * 57 + w];
            rsum += v; rmax = fmaxf(rmax, v);
        }
    }
    float tot = wave_sum(rsum);
    if (t < CL) {
        size_t idx = (size_t)b * CL + t;
        ph[idx] = rsum * (1.f / WB);
        mh[idx] = rmax;
        pw[idx] = csum * (1.f / HB);
        mw[idx] = cmax;
    }
    if (t == 0) gap[b] = tot * (1.f / PLANE);
}

// ---------------- Kernel 2: branch MLPs (+ gate g on branch 0) -------------------
__global__ __launch_bounds__(256) void k_branch(
        const float* __restrict__ ph, const float* __restrict__ pw,
        const float* __restrict__ mh, const float* __restrict__ mw,
        const float* __restrict__ gap,
        const float* __restrict__ w1, const float* __restrict__ b1,
        const float* __restrict__ gamma, const float* __restrict__ beta,
        const float* __restrict__ rmean, const float* __restrict__ rvar,
        const float* __restrict__ wh, const float* __restrict__ bh,
        const float* __restrict__ ww, const float* __restrict__ bw,
        const float* __restrict__ gw1, const float* __restrict__ gw2,
        const float* __restrict__ gb2,
        float* __restrict__ ah_m, float* __restrict__ aw_m,
        float* __restrict__ ah_x, float* __restrict__ aw_x,
        float* __restrict__ g) {
    int n = blockIdx.x;
    int br = blockIdx.y;                              // 0 = mean, 1 = max
    const float* pool_h = br ? mh : ph;
    const float* pool_w = br ? mw : pw;
    float* out_ah = br ? ah_x : ah_m;
    float* out_aw = br ? aw_x : aw_m;
    __shared__ float tile[CB * 113];                  // [c][l], l=0..111, +1 pad (113%32=17)
    __shared__ float lw1[8 * CB];
    __shared__ float y[8 * 112];
    __shared__ float hid[64];
    int t = threadIdx.x;                              // 256 threads

    for (int i = t; i < 8 * CB; i += 256) lw1[i] = w1[i];
    // stage both pool arrays coalesced (each 14336 contiguous floats = 3584 float4)
    const float4* ph4 = (const float4*)(pool_h + (size_t)n * (CB * CL));
    const float4* pw4 = (const float4*)(pool_w + (size_t)n * (CB * CL));
    for (int j = t; j < 3584; j += 256) {
        int c = j / 14, w4 = (j - c * 14) * 4;
        float4 v = ph4[j];
        float* d = &tile[c * 113 + w4];
        d[0] = v.x; d[1] = v.y; d[2] = v.z; d[3] = v.w;
        v = pw4[j];
        d = &tile[c * 113 + 56 + w4];
        d[0] = v.x; d[1] = v.y; d[2] = v.z; d[3] = v.w;
    }
    __syncthreads();

    // stage 1: y[m,l] = relu(BN(sum_c tile[c][l]*w1[m][c])). thread -> (group of 4 m, l)
    int grp = t / 112;                                // 0,1 active; 2 idle
    int l = t - grp * 112;
    if (grp < 2) {
        int m0 = grp * 4;
        float a0 = 0.f, a1 = 0.f, a2 = 0.f, a3 = 0.f;
        for (int c = 0; c < CB; ++c) {
            float v = tile[c * 113 + l];              // one LDS read feeds 4 MACs
            a0 += v * lw1[(m0 + 0) * CB + c];         // lw1: broadcast within group
            a1 += v * lw1[(m0 + 1) * CB + c];
            a2 += v * lw1[(m0 + 2) * CB + c];
            a3 += v * lw1[(m0 + 3) * CB + c];
        }
        float acc[4] = {a0, a1, a2, a3};
        #pragma unroll
        for (int k = 0; k < 4; ++k) {
            int m = m0 + k;
            float scale = gamma[m] * rsqrtf(rvar[m] + 1e-5f);
            float val = (acc[k] + b1[m] - rmean[m]) * scale + beta[m];
            y[m * 112 + l] = fmaxf(val, 0.f);
        }
    }
    __syncthreads();

    // stage 2: ah/aw sigmoid heads, coalesced writes
    for (int idx = t; idx < CB * CL; idx += 256) {
        int o = idx / CL, l2 = idx - o * CL;
        float acc = bh[o], acc2 = bw[o];
        #pragma unroll
        for (int m = 0; m < 8; ++m) {
            acc  += y[m * 112 + l2]      * wh[o * 8 + m];
            acc2 += y[m * 112 + CL + l2] * ww[o * 8 + m];
        }
        out_ah[(size_t)n * (CB * CL) + idx] = 1.f / (1.f + __expf(-acc));
        out_aw[(size_t)n * (CB * CL) + idx] = 1.f / (1.f + __expf(-acc2));
    }

    if (br == 0) {   // gate g[n]
        if (t < 64) {
            float a = 0.f;
            for (int c = 0; c < CB; ++c) a += gap[n * CB + c] * gw1[t * CB + c];
            hid[t] = fmaxf(a, 0.f);
        }
        __syncthreads();
        if (t == 0) {
            float l0 = gb2[0], l1 = gb2[1];
            for (int j = 0; j < 64; ++j) { l0 += hid[j] * gw2[j]; l1 += hid[j] * gw2[64 + j]; }
            float mx = fmaxf(l0, l1);
            float e0 = __expf(l0 - mx), e1 = __expf(l1 - mx);
            float inv = 1.f / (e0 + e1);
            g[n * 2]     = e0 * inv;
            g[n * 2 + 1] = e1 * inv;
        }
    }
}

// ---------------- Kernel 3: t[n,c] = mean_{h,w} x * attn -------------------------
__global__ __launch_bounds__(64) void k_tsum(const float* __restrict__ x,
        const float* __restrict__ ah_m, const float* __restrict__ aw_m,
        const float* __restrict__ ah_x, const float* __restrict__ aw_x,
        const float* __restrict__ g, float* __restrict__ tvec) {
    int b = blockIdx.x;
    int n = b >> 8;
    int t = threadIdx.x;
    __shared__ float cH0[CL], cW0[CL], cH1[CL], cW1[CL];
    if (t < CL) {
        size_t ab = (size_t)b * CL + t;
        float g0 = g[n * 2], g1 = g[n * 2 + 1];
        cH0[t] = ah_m[ab]; cW0[t] = g0 * aw_m[ab];
        cH1[t] = ah_x[ab]; cW1[t] = g1 * aw_x[ab];
    }
    __syncthreads();
    const float4* xp4 = (const float4*)(x + (size_t)b * PLANE);
    float acc = 0.f;
    for (int j = t; j < PLANE4; j += 64) {
        float4 v = xp4[j];
        int h = j / 14, w4 = (j - h * 14) * 4;
        float h0 = cH0[h], h1 = cH1[h];
        acc += v.x * (h0 * cW0[w4]     + h1 * cW1[w4]);
        acc += v.y * (h0 * cW0[w4 + 1] + h1 * cW1[w4 + 1]);
        acc += v.z * (h0 * cW0[w4 + 2] + h1 * cW1[w4 + 2]);
        acc += v.w * (h0 * cW0[w4 + 3] + h1 * cW1[w4 + 3]);
    }
    acc = wave_sum(acc);
    if (t == 0) tvec[b] = acc * (1.f / PLANE);
}

// ---------------- Kernel 4: s = sigmoid(relu(t@cw1.T)@cw2.T + cb2) ---------------
__global__ __launch_bounds__(256) void k_sgate(const float* __restrict__ tvec,
        const float* __restrict__ cw1, const float* __restrict__ cw2,
        const float* __restrict__ cb2, float* __restrict__ s) {
    int n = blockIdx.x;
    int t = threadIdx.x;
    __shared__ float hid[64];
    if (t < 64) {
        float a = 0.f;
        for (int c = 0; c < CB; ++c) a += tvec[n * CB + c] * cw1[t * CB + c];
        hid[t] = fmaxf(a, 0.f);
    }
    __syncthreads();
    float a = cb2[t];
    #pragma unroll 8
    for (int j = 0; j < 64; ++j) a += hid[j] * cw2[t * 64 + j];
    s[n * CB + t] = 1.f / (1.f + __expf(-a));
}

// ---------------- Kernel 5: out = x * (attn*s + 1) -------------------------------
__global__ __launch_bounds__(64) void k_final(const float* __restrict__ x,
        const float* __restrict__ ah_m, const float* __restrict__ aw_m,
        const float* __restrict__ ah_x, const float* __restrict__ aw_x,
        const float* __restrict__ g, const float* __restrict__ s,
        float* __restrict__ out) {
    int b = blockIdx.x;
    int n = b >> 8;
    int t = threadIdx.x;
    __shared__ float cH0[CL], cW0[CL], cH1[CL], cW1[CL];
    if (t < CL) {
        size_t ab = (size_t)b * CL + t;
        float g0 = g[n * 2], g1 = g[n * 2 + 1];
        float sv = s[b];
        cH0[t] = ah_m[ab]; cW0[t] = g0 * sv * aw_m[ab];
        cH1[t] = ah_x[ab]; cW1[t] = g1 * sv * aw_x[ab];
    }
    __syncthreads();
    const float4* xp4 = (const float4*)(x + (size_t)b * PLANE);
    float4* op4 = (float4*)(out + (size_t)b * PLANE);
    for (int j = t; j < PLANE4; j += 64) {
        float4 v = xp4[j];
        int h = j / 14, w4 = (j - h * 14) * 4;
        float h0 = cH0[h], h1 = cH1[h];
        float4 r;
        r.x = v.x * (h0 * cW0[w4]     + h1 * cW1[w4]     + 1.f);
        r.y = v.y * (h0 * cW0[w4 + 1] + h1 * cW1[w4 + 1] + 1.f);
        r.z = v.z * (h0 * cW0[w4 + 2] + h1 * cW1[w4 + 2] + 1.f);
        r.w = v.w * (h0 * cW0[w4 + 3] + h1 * cW1[w4 + 3] + 1.f);
        op4[j] = r;
    }
}

extern "C" void kernel_launch(void* const* d_in, const int* in_sizes, int n_in,
                              void* d_out, int out_size, void* d_ws, size_t ws_size,
                              hipStream_t stream) {
    const float* x     = (const float*)d_in[0];
    const float* w1    = (const float*)d_in[1];
    const float* b1    = (const float*)d_in[2];
    const float* gamma = (const float*)d_in[3];
    const float* beta  = (const float*)d_in[4];
    const float* rmean = (const float*)d_in[5];
    const float* rvar  = (const float*)d_in[6];
    const float* wh    = (const float*)d_in[7];
    const float* bh    = (const float*)d_in[8];
    const float* ww    = (const float*)d_in[9];
    const float* bw    = (const float*)d_in[10];
    const float* gw1   = (const float*)d_in[11];
    const float* gw2   = (const float*)d_in[12];
    const float* gb2   = (const float*)d_in[13];
    const float* cw1   = (const float*)d_in[14];
    const float* cw2   = (const float*)d_in[15];
    const float* cb2   = (const float*)d_in[16];
    float* out = (float*)d_out;

    float* w = (float*)d_ws;
    float* ph   = w;
    float* pw   = ph  + POOLSZ;
    float* mh   = pw  + POOLSZ;
    float* mw   = mh  + POOLSZ;
    float* ah_m = mw  + POOLSZ;
    float* aw_m = ah_m + POOLSZ;
    float* ah_x = aw_m + POOLSZ;
    float* aw_x = ah_x + POOLSZ;
    float* gap  = aw_x + POOLSZ;
    float* tvec = gap  + NB * CB;
    float* sbuf = tvec + NB * CB;
    float* gbuf = sbuf + NB * CB;

    int nplanes = NB * CB;   // 8192

    k_pool<<<nplanes, 64, 0, stream>>>(x, ph, pw, mh, mw, gap);
    k_branch<<<dim3(NB, 2), 256, 0, stream>>>(ph, pw, mh, mw, gap,
                                              w1, b1, gamma, beta, rmean, rvar,
                                              wh, bh, ww, bw, gw1, gw2, gb2,
                                              ah_m, aw_m, ah_x, aw_x, gbuf);
    k_tsum<<<nplanes, 64, 0, stream>>>(x, ah_m, aw_m, ah_x, aw_x, gbuf, tvec);
    k_sgate<<<NB, 256, 0, stream>>>(tvec, cw1, cw2, cb2, sbuf);
    k_final<<<nplanes, 64, 0, stream>>>(x, ah_m, aw_m, ah_x, aw_x, gbuf, sbuf, out);
}

// Round 5
// 289.908 us; speedup vs baseline: 1.1302x; 1.0653x over previous
//
#include <hip/hip_runtime.h>
#include <math.h>

#define NB 32
#define CB 256
#define HB 56
#define WB 56
#define PLANE 3136           // floats per (n,c) plane
#define PLANE4 784           // float4 per plane; rows = 14 float4, no wrap
#define CL 56
#define POOLSZ (NB*CB*CL)
#define YN (2*8*112)         // y floats per n: [br][m][l]

__device__ inline float wave_sum(float v) {
    #pragma unroll
    for (int o = 32; o; o >>= 1) v += __shfl_xor(v, o, 64);
    return v;
}

// ---------------- Kernel 1: pooling. 2048 blocks x 256 thr, 4 planes/block ------
__global__ __launch_bounds__(256) void k_pool(const float* __restrict__ x,
        float* __restrict__ ph, float* __restrict__ pw,
        float* __restrict__ mh, float* __restrict__ mw, float* __restrict__ gap) {
    int t = threadIdx.x;
    __shared__ float tile[HB * 57];          // stride 57: both scans conflict-free
    for (int i = 0; i < 4; ++i) {
        int p = blockIdx.x * 4 + i;
        const float4* xp4 = (const float4*)(x + (size_t)p * PLANE);
        for (int j = t; j < PLANE4; j += 256) {
            float4 v = xp4[j];
            int h = j / 14, w4 = (j - h * 14) * 4;
            float* d = &tile[h * 57 + w4];
            d[0] = v.x; d[1] = v.y; d[2] = v.z; d[3] = v.w;
        }
        __syncthreads();
        if (t < CL) {                        // wave 0, lanes 0-55: column scans
            float csum = 0.f, cmax = -INFINITY;
            #pragma unroll 8
            for (int h = 0; h < HB; ++h) {
                float v = tile[h * 57 + t];
                csum += v; cmax = fmaxf(cmax, v);
            }
            size_t idx = (size_t)p * CL + t;
            pw[idx] = csum * (1.f / HB);
            mw[idx] = cmax;
        } else if (t >= 64 && t < 128) {     // wave 1 ONLY (t=56..63 must idle!)
            int r = t - 64;
            float rsum = 0.f, rmax = -INFINITY;
            if (r < CL) {
                #pragma unroll 8
                for (int w = 0; w < WB; ++w) {
                    float v = tile[r * 57 + w];
                    rsum += v; rmax = fmaxf(rmax, v);
                }
                size_t idx = (size_t)p * CL + r;
                ph[idx] = rsum * (1.f / WB);
                mh[idx] = rmax;
            }
            float tot = wave_sum(rsum);      // lanes r>=56 contribute 0
            if (r == 0) gap[p] = tot * (1.f / PLANE);
        }
        __syncthreads();
    }
}

// ---------------- Kernel 2: y activations + gate g. grid (32,2) x 256 -----------
__global__ __launch_bounds__(256) void k_branch(
        const float* __restrict__ ph, const float* __restrict__ pw,
        const float* __restrict__ mh, const float* __restrict__ mw,
        const float* __restrict__ gap,
        const float* __restrict__ w1, const float* __restrict__ b1,
        const float* __restrict__ gamma, const float* __restrict__ beta,
        const float* __restrict__ rmean, const float* __restrict__ rvar,
        const float* __restrict__ gw1, const float* __restrict__ gw2,
        const float* __restrict__ gb2,
        float* __restrict__ yout, float* __restrict__ g) {
    int n = blockIdx.x;
    int br = blockIdx.y;
    const float* pool_h = br ? mh : ph;
    const float* pool_w = br ? mw : pw;
    __shared__ float tile[CB * 113];         // [c][l], 113 odd -> conflict-free
    __shared__ float lw1[8 * CB];
    __shared__ float hid[64];
    int t = threadIdx.x;

    for (int i = t; i < 8 * CB; i += 256) lw1[i] = w1[i];
    const float4* ph4 = (const float4*)(pool_h + (size_t)n * (CB * CL));
    const float4* pw4 = (const float4*)(pool_w + (size_t)n * (CB * CL));
    for (int j = t; j < 3584; j += 256) {
        int c = j / 14, w4 = (j - c * 14) * 4;
        float4 v = ph4[j];
        float* d = &tile[c * 113 + w4];
        d[0] = v.x; d[1] = v.y; d[2] = v.z; d[3] = v.w;
        v = pw4[j];
        d = &tile[c * 113 + 56 + w4];
        d[0] = v.x; d[1] = v.y; d[2] = v.z; d[3] = v.w;
    }
    __syncthreads();

    int grp = t / 112, l = t - grp * 112;    // grp 0,1 active (4 m each); grp 2 idle
    if (grp < 2) {
        int m0 = grp * 4;
        float a0 = 0.f, a1 = 0.f, a2 = 0.f, a3 = 0.f;
        #pragma unroll 8
        for (int c = 0; c < CB; ++c) {
            float v = tile[c * 113 + l];
            a0 += v * lw1[(m0 + 0) * CB + c];
            a1 += v * lw1[(m0 + 1) * CB + c];
            a2 += v * lw1[(m0 + 2) * CB + c];
            a3 += v * lw1[(m0 + 3) * CB + c];
        }
        float acc[4] = {a0, a1, a2, a3};
        #pragma unroll
        for (int k = 0; k < 4; ++k) {
            int m = m0 + k;
            float scale = gamma[m] * rsqrtf(rvar[m] + 1e-5f);
            float val = (acc[k] + b1[m] - rmean[m]) * scale + beta[m];
            yout[(size_t)(n * 2 + br) * 896 + m * 112 + l] = fmaxf(val, 0.f);
        }
    }

    if (br == 0) {                           // gate g[n] (block-uniform branch)
        if (t >= 128 && t < 192) {
            int j = t - 128;
            float acc = 0.f;
            for (int c = 0; c < CB; ++c) acc += gap[n * CB + c] * gw1[j * CB + c];
            hid[j] = fmaxf(acc, 0.f);
        }
        __syncthreads();
        if (t == 0) {
            float l0 = gb2[0], l1 = gb2[1];
            for (int j = 0; j < 64; ++j) { l0 += hid[j] * gw2[j]; l1 += hid[j] * gw2[64 + j]; }
            float mx = fmaxf(l0, l1);
            float e0 = __expf(l0 - mx), e1 = __expf(l1 - mx);
            float inv = 1.f / (e0 + e1);
            g[n * 2]     = e0 * inv;
            g[n * 2 + 1] = e1 * inv;
        }
    }
}

// ---- shared helper: build per-c coefficient tables from y ----------------------
__device__ inline void build_coeffs(const float* __restrict__ ybuf,  // LDS [2][8][112]
        const float* __restrict__ wh, const float* __restrict__ bh,
        const float* __restrict__ ww, const float* __restrict__ bw,
        float g0, float g1, int c0, int t,
        float (*cH0)[CL], float (*cW0)[CL], float (*cH1)[CL], float (*cW1)[CL]) {
    if (t < 224) {
        int ci = t / CL, l = t - ci * CL;
        int c = c0 + ci;
        float whv[8], wwv[8];
        #pragma unroll
        for (int m = 0; m < 8; ++m) { whv[m] = wh[c * 8 + m]; wwv[m] = ww[c * 8 + m]; }
        float h0 = bh[c], w0 = bw[c], h1 = bh[c], w1v = bw[c];
        #pragma unroll
        for (int m = 0; m < 8; ++m) {
            h0  += ybuf[m * 112 + l]        * whv[m];
            w0  += ybuf[m * 112 + 56 + l]   * wwv[m];
            h1  += ybuf[896 + m * 112 + l]      * whv[m];
            w1v += ybuf[896 + m * 112 + 56 + l] * wwv[m];
        }
        cH0[ci][l] = 1.f / (1.f + __expf(-h0));
        cW0[ci][l] = g0 / (1.f + __expf(-w0));
        cH1[ci][l] = 1.f / (1.f + __expf(-h1));
        cW1[ci][l] = g1 / (1.f + __expf(-w1v));
    }
}

// ---------------- Kernel 3: tvec[p] = mean(x*attn). 2048 x 256, 4 planes --------
__global__ __launch_bounds__(256) void k_tsum(const float* __restrict__ x,
        const float* __restrict__ y, const float* __restrict__ g,
        const float* __restrict__ wh, const float* __restrict__ bh,
        const float* __restrict__ ww, const float* __restrict__ bw,
        float* __restrict__ tvec) {
    int t = threadIdx.x;
    int p0 = blockIdx.x * 4;
    int n = p0 >> 8, c0 = p0 & 255;
    __shared__ float ybuf[YN];
    __shared__ float cH0[4][CL], cW0[4][CL], cH1[4][CL], cW1[4][CL];
    __shared__ float part[4][4];
    for (int i = t; i < YN; i += 256) ybuf[i] = y[(size_t)n * YN + i];
    __syncthreads();
    build_coeffs(ybuf, wh, bh, ww, bw, g[n * 2], g[n * 2 + 1], c0, t, cH0, cW0, cH1, cW1);
    __syncthreads();
    float acc[4] = {0.f, 0.f, 0.f, 0.f};
    #pragma unroll
    for (int i = 0; i < 4; ++i) {
        const float4* xp4 = (const float4*)(x + (size_t)(p0 + i) * PLANE);
        for (int j = t; j < PLANE4; j += 256) {
            float4 v = xp4[j];
            int h = j / 14, w4 = (j - h * 14) * 4;
            float h0 = cH0[i][h], h1 = cH1[i][h];
            acc[i] += v.x * (h0 * cW0[i][w4]     + h1 * cW1[i][w4]);
            acc[i] += v.y * (h0 * cW0[i][w4 + 1] + h1 * cW1[i][w4 + 1]);
            acc[i] += v.z * (h0 * cW0[i][w4 + 2] + h1 * cW1[i][w4 + 2]);
            acc[i] += v.w * (h0 * cW0[i][w4 + 3] + h1 * cW1[i][w4 + 3]);
        }
    }
    int w = t >> 6, lane = t & 63;
    #pragma unroll
    for (int i = 0; i < 4; ++i) {
        float s = wave_sum(acc[i]);
        if (lane == 0) part[i][w] = s;
    }
    __syncthreads();
    if (t < 4)
        tvec[p0 + t] = (part[t][0] + part[t][1] + part[t][2] + part[t][3]) * (1.f / PLANE);
}

// ---------------- Kernel 4: out = x*(attn*s+1). 2048 x 256, 4 planes ------------
__global__ __launch_bounds__(256) void k_final(const float* __restrict__ x,
        const float* __restrict__ y, const float* __restrict__ g,
        const float* __restrict__ wh, const float* __restrict__ bh,
        const float* __restrict__ ww, const float* __restrict__ bw,
        const float* __restrict__ tvec,
        const float* __restrict__ cw1, const float* __restrict__ cw2,
        const float* __restrict__ cb2, float* __restrict__ out) {
    int t = threadIdx.x;
    int p0 = blockIdx.x * 4;
    int n = p0 >> 8, c0 = p0 & 255;
    __shared__ float ybuf[YN];
    __shared__ float cH0[4][CL], cW0[4][CL], cH1[4][CL], cW1[4][CL];
    __shared__ float hid[64];
    __shared__ float sS[4];
    for (int i = t; i < YN; i += 256) ybuf[i] = y[(size_t)n * YN + i];
    if (t >= 192) {                          // wave 3: s-gate hidden layer
        int j = t - 192;
        float acc = 0.f;
        for (int c = 0; c < CB; ++c) acc += tvec[n * CB + c] * cw1[j * CB + c];
        hid[j] = fmaxf(acc, 0.f);
    }
    __syncthreads();
    if (t < 4) {                             // s for this block's 4 channels
        int c = c0 + t;
        float acc = cb2[c];
        #pragma unroll 8
        for (int j = 0; j < 64; ++j) acc += hid[j] * cw2[c * 64 + j];
        sS[t] = 1.f / (1.f + __expf(-acc));
    }
    build_coeffs(ybuf, wh, bh, ww, bw, g[n * 2], g[n * 2 + 1], c0, t, cH0, cW0, cH1, cW1);
    __syncthreads();
    #pragma unroll
    for (int i = 0; i < 4; ++i) {
        float sv = sS[i];
        const float4* xp4 = (const float4*)(x + (size_t)(p0 + i) * PLANE);
        float4* op4 = (float4*)(out + (size_t)(p0 + i) * PLANE);
        for (int j = t; j < PLANE4; j += 256) {
            float4 v = xp4[j];
            int h = j / 14, w4 = (j - h * 14) * 4;
            float h0 = cH0[i][h] * sv, h1 = cH1[i][h] * sv;
            float4 r;
            r.x = v.x * (h0 * cW0[i][w4]     + h1 * cW1[i][w4]     + 1.f);
            r.y = v.y * (h0 * cW0[i][w4 + 1] + h1 * cW1[i][w4 + 1] + 1.f);
            r.z = v.z * (h0 * cW0[i][w4 + 2] + h1 * cW1[i][w4 + 2] + 1.f);
            r.w = v.w * (h0 * cW0[i][w4 + 3] + h1 * cW1[i][w4 + 3] + 1.f);
            op4[j] = r;
        }
    }
}

extern "C" void kernel_launch(void* const* d_in, const int* in_sizes, int n_in,
                              void* d_out, int out_size, void* d_ws, size_t ws_size,
                              hipStream_t stream) {
    const float* x     = (const float*)d_in[0];
    const float* w1    = (const float*)d_in[1];
    const float* b1    = (const float*)d_in[2];
    const float* gamma = (const float*)d_in[3];
    const float* beta  = (const float*)d_in[4];
    const float* rmean = (const float*)d_in[5];
    const float* rvar  = (const float*)d_in[6];
    const float* wh    = (const float*)d_in[7];
    const float* bh    = (const float*)d_in[8];
    const float* ww    = (const float*)d_in[9];
    const float* bw    = (const float*)d_in[10];
    const float* gw1   = (const float*)d_in[11];
    const float* gw2   = (const float*)d_in[12];
    const float* gb2   = (const float*)d_in[13];
    const float* cw1   = (const float*)d_in[14];
    const float* cw2   = (const float*)d_in[15];
    const float* cb2   = (const float*)d_in[16];
    float* out = (float*)d_out;

    float* w = (float*)d_ws;
    float* ph   = w;
    float* pw   = ph + POOLSZ;
    float* mh   = pw + POOLSZ;
    float* mw   = mh + POOLSZ;
    float* ybuf = mw + POOLSZ;          // NB * YN
    float* gap  = ybuf + NB * YN;       // NB*CB
    float* tvec = gap + NB * CB;        // NB*CB
    float* gbuf = tvec + NB * CB;       // NB*2

    k_pool<<<2048, 256, 0, stream>>>(x, ph, pw, mh, mw, gap);
    k_branch<<<dim3(NB, 2), 256, 0, stream>>>(ph, pw, mh, mw, gap,
                                              w1, b1, gamma, beta, rmean, rvar,
                                              gw1, gw2, gb2, ybuf, gbuf);
    k_tsum<<<2048, 256, 0, stream>>>(x, ybuf, gbuf, wh, bh, ww, bw, tvec);
    k_final<<<2048, 256, 0, stream>>>(x, ybuf, gbuf, wh, bh, ww, bw,
                                      tvec, cw1, cw2, cb2, out);
}